// Round 2
// baseline (229.031 us; speedup 1.0000x reference)
//
#include <hip/hip_runtime.h>

#define B_    16
#define CIN   64
#define COUT  128
#define H_    32
#define W_    32
#define HP    34            // halo-padded spatial dim
#define XCH   136           // 16B chunks per padded qx row = 2*2*34
#define NBLK  512           // (b,y) grid; 2 blocks/CU -> all 512 co-resident

typedef __attribute__((ext_vector_type(4)))  int int4v;    // 16 int8 = 4 VGPRs
typedef __attribute__((ext_vector_type(16))) int int16v;   // 32x32 i8 MFMA C/D

// ---------------------------------------------------------------------------
// Hand-rolled grid barrier (replaces cg::grid.sync(), which cost ~45 us/sync
// at 512 blocks in round 1). Two-level: 8 leaf counters (64 arrivals each,
// parallel cachelines) -> 1 root counter. Counters live in d_ws (HBM/IC, not
// host-coherent memory). __threadfence() provides agent-scope release/acquire
// (L2 writeback + invalidate) so pre-barrier stores (bmx/bmw/qx/qw) are
// visible across non-coherent per-XCD L2s. Counters are monotonic across the
// kernel's barriers; zeroed by a hipMemsetAsync node before launch.
// idx = 1-based barrier index.
// ---------------------------------------------------------------------------
__device__ __forceinline__ void grid_barrier(unsigned* __restrict__ leaf,
                                             unsigned* __restrict__ root,
                                             unsigned idx) {
  __syncthreads();
  __threadfence();                          // release: make prior writes agent-visible
  if (threadIdx.x == 0) {
    unsigned r = __hip_atomic_fetch_add(&leaf[blockIdx.x & 7], 1u,
                                        __ATOMIC_RELAXED,
                                        __HIP_MEMORY_SCOPE_AGENT);
    if (r == idx * 64u - 1u)                // last arriver of this leaf group
      __hip_atomic_fetch_add(root, 1u, __ATOMIC_RELAXED,
                             __HIP_MEMORY_SCOPE_AGENT);
    while (__hip_atomic_load(root, __ATOMIC_RELAXED,
                             __HIP_MEMORY_SCOPE_AGENT) < idx * 8u)
      __builtin_amdgcn_s_sleep(2);
  }
  __syncthreads();
  __threadfence();                          // acquire: invalidate stale cache lines
}

// ---------------------------------------------------------------------------
// Single fused kernel (plain launch, persistent grid):
//   Phase 1: per-block max|x|, max|w| -> bmx[512], bmw[512]
//   barrier -> fold partials to global scales (in-register)
//   Phase 2: quantize exactly like the reference (IEEE div by max/127, rintf,
//            clip +-127), pack qx (halo-padded, MFMA lane order) and qw.
//   barrier
//   Phase 3: conv as 32x32x32 INT8 MFMA (exact: |q|<=127, i32 accum), scaled
//            epilogue with the scales still in registers.
// ---------------------------------------------------------------------------
__global__ __launch_bounds__(256, 2) void fused_conv_kernel(
    const float* __restrict__ x, const float* __restrict__ w,
    const float* __restrict__ bias,
    float* __restrict__ bmx, float* __restrict__ bmw,
    char* __restrict__ qx,   // s8 [16][34][2][2][34][16]
    char* __restrict__ qw,   // s8 [9][2][2][128][16]
    float* __restrict__ out,
    unsigned* __restrict__ leaf, unsigned* __restrict__ root) {
  const int t    = threadIdx.x;
  const int bb   = blockIdx.x;
  const int lane = t & 63;
  const int wid  = t >> 6;

  __shared__ __align__(16) char lds[W_ * 80];  // [x][cin], pad 64->80
  __shared__ float smx[4], smw[4];

  // ---------------- Phase 1: block-partial maxabs ----------------
  {
    const float4* __restrict__ x4 = (const float4*)x;
    const float4* __restrict__ w4 = (const float4*)w;
    const int g = bb * 256 + t;                // [0, 131072)
    float mx, mw = 0.0f;
    float4 v0 = x4[g];
    float4 v1 = x4[g + 131072];                // 262144 float4 total
    mx = fmaxf(fmaxf(fmaxf(fabsf(v0.x), fabsf(v0.y)),
                     fmaxf(fabsf(v0.z), fabsf(v0.w))),
               fmaxf(fmaxf(fabsf(v1.x), fabsf(v1.y)),
                     fmaxf(fabsf(v1.z), fabsf(v1.w))));
    if (g < COUT * CIN * 9 / 4) {              // 18432 float4 of w
      float4 v = w4[g];
      mw = fmaxf(fmaxf(fabsf(v.x), fabsf(v.y)),
                 fmaxf(fabsf(v.z), fabsf(v.w)));
    }
#pragma unroll
    for (int off = 32; off > 0; off >>= 1) {
      mx = fmaxf(mx, __shfl_down(mx, off, 64));
      mw = fmaxf(mw, __shfl_down(mw, off, 64));
    }
    if (lane == 0) { smx[wid] = mx; smw[wid] = mw; }
    __syncthreads();
    if (t == 0) {
#pragma unroll
      for (int i = 1; i < 4; ++i) { mx = fmaxf(mx, smx[i]); mw = fmaxf(mw, smw[i]); }
      bmx[bb] = mx;
      bmw[bb] = mw;
    }
  }

  grid_barrier(leaf, root, 1u);

  // ---------------- fold 512 partials -> global scales (all lanes) --------
  float gmx = 0.0f, gmw = 0.0f;
#pragma unroll
  for (int i = 0; i < 8; ++i) {
    gmx = fmaxf(gmx, bmx[lane + 64 * i]);
    gmw = fmaxf(gmw, bmw[lane + 64 * i]);
  }
#pragma unroll
  for (int off = 32; off > 0; off >>= 1) {
    gmx = fmaxf(gmx, __shfl_down(gmx, off, 64));
    gmw = fmaxf(gmw, __shfl_down(gmw, off, 64));
  }
  gmx = __shfl(gmx, 0, 64);
  gmw = __shfl(gmw, 0, 64);
  const float sx = gmx / 127.0f;
  const float sw = gmw / 127.0f;

  // ---------------- Phase 2: quantize + pack ----------------
  const int b = bb >> 5, y = bb & 31;
  {
#pragma unroll
    for (int k = 0; k < 8; ++k) {
      const int u = t + k * 256;               // [0, 2048)
      const int cin = u >> 5, xx = u & 31;     // coalesced along x
      float q = rintf(x[((b * CIN + cin) * H_ + y) * W_ + xx] / sx);
      q = fminf(fmaxf(q, -127.0f), 127.0f);
      lds[xx * 80 + cin] = (char)(int)q;
    }
    // weights: 512 blocks x 144 elements = 73728
    if (t < 144) {
      const int i = bb * 144 + t;
      float q = rintf(w[i] / sw);
      q = fminf(fmaxf(q, -127.0f), 127.0f);
      // i = ((o*64 + c)*3 + kh)*3 + kw
      const int kw = i % 3; int j = i / 3;
      const int kh = j % 3; j /= 3;
      const int c = j & 63; const int o = j >> 6;
      const int sidx = kh * 3 + kw;
      const int c32 = c >> 5, kb = (c >> 4) & 1, e = c & 15;
      qw[(size_t)(((sidx * 2 + c32) * 2 + kb) * 128 + o) * 16 + e] = (char)(int)q;
    }
    __syncthreads();
    // write 136 16-B chunks: c = (c32*2+kb)*34 + xs
    char* row = qx + (size_t)(b * HP + y + 1) * (XCH * 16);
    if (t < XCH) {
      const int c32 = t / 68;
      const int r   = t - c32 * 68;
      const int kb  = r / 34;
      const int xs  = r - kb * 34;
      uint4 v; v.x = v.y = v.z = v.w = 0;
      if (xs >= 1 && xs <= 32)
        v = *(const uint4*)(&lds[(xs - 1) * 80 + c32 * 32 + kb * 16]);
      *(uint4*)(row + t * 16) = v;
    }
    // zero halo rows (32 of them) folded into blocks 0..31
    if (bb < 32 && t < XCH) {
      const int b2 = bb >> 1, yy = (bb & 1) ? 33 : 0;
      char* hrow = qx + (size_t)(b2 * HP + yy) * (XCH * 16);
      uint4 z; z.x = z.y = z.z = z.w = 0;
      *(uint4*)(hrow + t * 16) = z;
    }
  }

  grid_barrier(leaf, root, 2u);

  // ---------------- Phase 3: INT8 MFMA conv ----------------
  // Wave = 32 pixels (row y) x 32 couts. A frag: A[m=lane&31][k=(lane>>5)*16+j]
  // B: B[k][n=lane&31]. D: col=lane&31 (pixel x),
  // row=(reg&3)+8*(reg>>2)+4*(lane>>5) (cout). Two acc chains, exact int sum.
  {
    const int col = lane & 31;                 // pixel x / cout row
    const int kb  = lane >> 5;                 // k-half within 32
    const int co0 = wid * 32;

    int16v acc0 = (int16v)0, acc1 = (int16v)0;

    // qx byte offsets: ((((b*34 + y+kh)*2 + c32)*2 + kb)*34 + col+kw)*16
    const char* __restrict__ xp =
        qx + ((size_t)(b * HP + y) * 4 + kb) * 544 + col * 16;
    // qw byte offsets: (((s*2 + c32)*2 + kb)*128 + co0+col)*16
    const char* __restrict__ wp = qw + (kb * 128 + co0 + col) * 16;

#pragma unroll
    for (int kh = 0; kh < 3; ++kh) {
      const char* __restrict__ xr = xp + (size_t)kh * (4 * 544);
#pragma unroll
      for (int kw = 0; kw < 3; ++kw) {
        const int s = kh * 3 + kw;
#pragma unroll
        for (int c32 = 0; c32 < 2; ++c32) {
          int4v a  = *(const int4v*)(wp + (s * 2 + c32) * 4096);
          int4v bf = *(const int4v*)(xr + c32 * 1088 + kw * 16);
          if (((s * 2 + c32) & 1) == 0)
            acc0 = __builtin_amdgcn_mfma_i32_32x32x32_i8(a, bf, acc0, 0, 0, 0);
          else
            acc1 = __builtin_amdgcn_mfma_i32_32x32x32_i8(a, bf, acc1, 0, 0, 0);
        }
      }
    }

    const float sc = sx * sw;
#pragma unroll
    for (int r = 0; r < 16; ++r) {
      const int row  = (r & 3) + 8 * (r >> 2) + 4 * kb;
      const int cout = co0 + row;
      out[((b * COUT + cout) << 10) + y * W_ + col] =
          sc * (float)(acc0[r] + acc1[r]) + bias[cout];
    }
  }
}

// ---------------------------------------------------------------------------
extern "C" void kernel_launch(void* const* d_in, const int* in_sizes, int n_in,
                              void* d_out, int out_size, void* d_ws, size_t ws_size,
                              hipStream_t stream) {
  const float* x    = (const float*)d_in[0];
  const float* w    = (const float*)d_in[1];
  const float* bias = (const float*)d_in[2];
  float* out = (float*)d_out;

  // ws: counters 128 B (leaf[8] @0, root @64, zeroed each launch) |
  //     bmx[512] @128 | bmw[512] | qx s8 [16][34][136][16] @8192 | qw s8
  unsigned* leaf = (unsigned*)d_ws;
  unsigned* root = (unsigned*)((char*)d_ws + 64);
  float* bmx = (float*)((char*)d_ws + 128);
  float* bmw = bmx + 512;
  char* qx = (char*)d_ws + 8192;
  char* qw = qx + (size_t)B_ * HP * XCH * 16;

  hipMemsetAsync(d_ws, 0, 128, stream);      // zero barrier counters (poisoned ws)
  fused_conv_kernel<<<NBLK, 256, 0, stream>>>(x, w, bias, bmx, bmw, qx, qw,
                                              out, leaf, root);
}

// Round 3
// 109.025 us; speedup vs baseline: 2.1007x; 2.1007x over previous
//
#include <hip/hip_runtime.h>

#define B_    16
#define CIN   64
#define COUT  128
#define H_    32
#define W_    32
#define NBLK  512           // (b:16, yq:8, cq:4); 2 blocks/CU -> all co-resident

typedef __attribute__((ext_vector_type(4)))  int int4v;    // 16 int8 = 4 VGPRs
typedef __attribute__((ext_vector_type(16))) int int16v;   // 32x32 i8 MFMA C/D

__device__ __forceinline__ float fmax4(float4 v) {
  return fmaxf(fmaxf(fabsf(v.x), fabsf(v.y)), fmaxf(fabsf(v.z), fabsf(v.w)));
}

// ---------------------------------------------------------------------------
// Single fused kernel, ONE grid barrier protecting only gmx/gmw (8 bytes).
// All quantized data (qw, qx) is BLOCK-LOCAL in LDS -> no cross-block
// publication, no cache fences. Round-2 lesson: agent-scope relaxed spin
// loads can hit stale per-XCD L2 (non-coherent) -> observe release only on
// eviction (~80us). Fix: SYSTEM scope on every cross-block atomic (sc0 sc1,
// served at the IC coherence point).
//
// Block (b, yq, cq): 4 output rows yq*4..+3, 32 couts cq*32..+31, all pixels.
//   Phase 1: partial max|x| (1/512 slice), max|w| (blocks 0..71) ->
//            system atomic_umax on float bits (all >=0 -> bits monotone).
//   Barrier: leaf[bb&31] (16 arrivals, 128B-spaced lines) -> root (32);
//            spin system-scope; then read gmx/gmw system-scope.
//   Phase 2: waves 0-1: quantize this block's 32 couts of w -> LDS qw_l
//            (thread = (o,c32,kb): 144 contiguous floats = 36 float4 loads,
//            static-unrolled repack -> 9 ds_write_b128).
//            waves 2-3: quantize 6 halo rows of x -> LDS qx_l (chunk = 16
//            cin bytes, 16 stride-4KB loads, lanes coalesced along xs).
//   Phase 3: 18 x mfma_i32_32x32x32_i8 per wave from LDS (exact i32 accum),
//            scaled epilogue. Same verified fragment/D layout as before.
// LDS: qw_l 18432 + qx_l 13056 + reduce scratch ~= 31.6 KB -> 2 blocks/CU.
// ---------------------------------------------------------------------------
__global__ __launch_bounds__(256, 2) void fused_conv_kernel(
    const float* __restrict__ x, const float* __restrict__ w,
    const float* __restrict__ bias, float* __restrict__ out,
    unsigned* __restrict__ leaf,    // 32 counters, 128-B spaced
    unsigned* __restrict__ root,
    unsigned* __restrict__ gbits) { // [0]=max|x| bits, [1]=max|w| bits
  const int t    = threadIdx.x;
  const int bb   = blockIdx.x;
  const int lane = t & 63;
  const int wid  = t >> 6;

  __shared__ __align__(16) char qw_l[18432];  // [s:9][c32:2][kb:2][o:32][16]
  __shared__ __align__(16) char qx_l[13056];  // [r:6][c32:2][kb:2][xs:34][16]
  __shared__ float smax[8];
  __shared__ float sscale[2];

  const int b  = bb >> 5;          // batch
  const int yq = (bb >> 2) & 7;    // y quad (rows yq*4 .. yq*4+3)
  const int cq = bb & 3;           // cout quarter (couts cq*32 .. +31)

  // ---------------- Phase 1: partial maxabs -> system atomic umax ---------
  {
    const float4* __restrict__ x4 = (const float4*)x;
    const float4* __restrict__ w4 = (const float4*)w;
    const int g = bb * 256 + t;                // [0, 131072)
    float4 v0 = x4[g];
    float4 v1 = x4[g + 131072];                // 262144 float4 total
    float mx = fmaxf(fmax4(v0), fmax4(v1));
    float mw = 0.0f;
    if (g < COUT * CIN * 9 / 4) mw = fmax4(w4[g]);   // 18432 float4 of w
#pragma unroll
    for (int off = 32; off > 0; off >>= 1) {
      mx = fmaxf(mx, __shfl_down(mx, off, 64));
      mw = fmaxf(mw, __shfl_down(mw, off, 64));
    }
    if (lane == 0) { smax[wid] = mx; smax[4 + wid] = mw; }
    __syncthreads();
    if (t == 0) {
#pragma unroll
      for (int i = 1; i < 4; ++i) {
        mx = fmaxf(mx, smax[i]);
        mw = fmaxf(mw, smax[4 + i]);
      }
      __hip_atomic_fetch_max(&gbits[0], __float_as_uint(mx),
                             __ATOMIC_RELAXED, __HIP_MEMORY_SCOPE_SYSTEM);
      __hip_atomic_fetch_max(&gbits[1], __float_as_uint(mw),
                             __ATOMIC_RELAXED, __HIP_MEMORY_SCOPE_SYSTEM);
    }
  }

  // ---------------- grid barrier (system scope, no cache fences) ----------
  if (t == 0) {
    asm volatile("s_waitcnt vmcnt(0)" ::: "memory");  // umax at IC before arrival
    unsigned r = __hip_atomic_fetch_add(&leaf[(bb & 31) * 32], 1u,
                                        __ATOMIC_RELAXED,
                                        __HIP_MEMORY_SCOPE_SYSTEM);
    if (r == 15u)                               // last arriver of this leaf
      __hip_atomic_fetch_add(root, 1u, __ATOMIC_RELAXED,
                             __HIP_MEMORY_SCOPE_SYSTEM);
    while (__hip_atomic_load(root, __ATOMIC_RELAXED,
                             __HIP_MEMORY_SCOPE_SYSTEM) < 32u)
      __builtin_amdgcn_s_sleep(2);
    sscale[0] = __uint_as_float(__hip_atomic_load(
                    &gbits[0], __ATOMIC_RELAXED, __HIP_MEMORY_SCOPE_SYSTEM)) /
                127.0f;
    sscale[1] = __uint_as_float(__hip_atomic_load(
                    &gbits[1], __ATOMIC_RELAXED, __HIP_MEMORY_SCOPE_SYSTEM)) /
                127.0f;
  }
  __syncthreads();
  const float sx = sscale[0];
  const float sw = sscale[1];

  // ---------------- Phase 2: quantize block-local slices into LDS ---------
  if (t < 128) {
    // weights: thread = (o, c32, kb); 144 contiguous floats of w.
    const int o = t & 31, c32 = (t >> 5) & 1, kb = t >> 6;
    const float4* __restrict__ w4 = (const float4*)w;
    const int base4 = (((cq * 32 + o) * 64 + c32 * 32 + kb * 16) * 9) >> 2;
    int qd[36];                                 // [s:9][e4:4], static-indexed
#pragma unroll
    for (int k = 0; k < 36; ++k) {
      float4 v = w4[base4 + k];
#pragma unroll
      for (int j = 0; j < 4; ++j) {
        const int idx = 4 * k + j;              // = e*9 + s
        const int e = idx / 9, s = idx - e * 9;
        const float vv = (j == 0) ? v.x : (j == 1) ? v.y : (j == 2) ? v.z : v.w;
        float q = rintf(vv / sw);
        q = fminf(fmaxf(q, -127.0f), 127.0f);
        const unsigned byte = (unsigned)((int)q & 255) << ((e & 3) * 8);
        const int d = s * 4 + (e >> 2);
        if ((e & 3) == 0) qd[d] = (int)byte;    // first touch per dword
        else             qd[d] |= (int)byte;
      }
    }
#pragma unroll
    for (int s = 0; s < 9; ++s) {
      int4v val = {qd[s * 4], qd[s * 4 + 1], qd[s * 4 + 2], qd[s * 4 + 3]};
      *(int4v*)(qw_l + (((s * 2 + c32) * 2 + kb) * 32 + o) * 16) = val;
    }
  } else {
    // x rows yq*4-1 .. yq*4+4 (6 rows incl halo), 816 16-B chunks.
    const int t2 = t - 128;
#pragma unroll
    for (int k = 0; k < 7; ++k) {
      const int ch = t2 + k * 128;
      if (ch < 816) {
        const int r = ch / 136, rem = ch - r * 136;
        const int c32 = rem / 68, rem2 = rem - c32 * 68;
        const int kb = rem2 / 34, xs = rem2 - kb * 34;
        const int yy = yq * 4 - 1 + r;
        const int xx = xs - 1;
        unsigned d0 = 0, d1 = 0, d2 = 0, d3 = 0;
        if (yy >= 0 && yy <= 31 && xx >= 0 && xx <= 31) {
          const float* __restrict__ xp =
              x + ((size_t)((b * CIN + c32 * 32 + kb * 16) * H_ + yy) * W_) + xx;
#pragma unroll
          for (int e = 0; e < 16; ++e) {        // cin stride = H*W = 1024
            float q = rintf(xp[e * 1024] / sx);
            q = fminf(fmaxf(q, -127.0f), 127.0f);
            const unsigned byte = (unsigned)((int)q & 255) << ((e & 3) * 8);
            if (e < 4) d0 |= byte; else if (e < 8) d1 |= byte;
            else if (e < 12) d2 |= byte; else d3 |= byte;
          }
        }
        int4v val = {(int)d0, (int)d1, (int)d2, (int)d3};
        *(int4v*)(qx_l + (((r * 2 + c32) * 2 + kb) * 34 + xs) * 16) = val;
      }
    }
  }
  __syncthreads();

  // ---------------- Phase 3: INT8 MFMA conv from LDS ----------------
  // Wave wid handles row y = yq*4+wid, couts cq*32..+31, 32 pixels.
  // A frag: A[m=lane&31][k=(lane>>5)*16+j]; B: B[k][n=lane&31].
  // D: col=lane&31 (pixel x), row=(reg&3)+8*(reg>>2)+4*(lane>>5) (cout).
  {
    const int col = lane & 31;                 // pixel x / cout_local
    const int kb  = lane >> 5;                 // k-half within 32
    const int wy  = wid;

    int16v acc0 = (int16v)0, acc1 = (int16v)0;

#pragma unroll
    for (int kh = 0; kh < 3; ++kh) {
      const int r = wy + kh;                   // qx_l row (yy = yq*4+wy+kh-1)
#pragma unroll
      for (int kw = 0; kw < 3; ++kw) {
        const int s = kh * 3 + kw;
#pragma unroll
        for (int c32 = 0; c32 < 2; ++c32) {
          int4v a  = *(const int4v*)(qw_l + (((s * 2 + c32) * 2 + kb) * 32 + col) * 16);
          int4v bf = *(const int4v*)(qx_l + (((r * 2 + c32) * 2 + kb) * 34 + col + kw) * 16);
          if (((s * 2 + c32) & 1) == 0)
            acc0 = __builtin_amdgcn_mfma_i32_32x32x32_i8(a, bf, acc0, 0, 0, 0);
          else
            acc1 = __builtin_amdgcn_mfma_i32_32x32x32_i8(a, bf, acc1, 0, 0, 0);
        }
      }
    }

    const float sc = sx * sw;
    const int y = yq * 4 + wy;
#pragma unroll
    for (int rg = 0; rg < 16; ++rg) {
      const int row  = (rg & 3) + 8 * (rg >> 2) + 4 * kb;
      const int cout = cq * 32 + row;
      out[((b * COUT + cout) << 10) + y * W_ + col] =
          sc * (float)(acc0[rg] + acc1[rg]) + bias[cout];
    }
  }
}

// ---------------------------------------------------------------------------
extern "C" void kernel_launch(void* const* d_in, const int* in_sizes, int n_in,
                              void* d_out, int out_size, void* d_ws, size_t ws_size,
                              hipStream_t stream) {
  const float* x    = (const float*)d_in[0];
  const float* w    = (const float*)d_in[1];
  const float* bias = (const float*)d_in[2];
  float* out = (float*)d_out;

  // ws: leaf[32] on 128-B-spaced lines @0 (4 KB) | root @4096 | gbits @4352
  unsigned* leaf  = (unsigned*)d_ws;
  unsigned* root  = (unsigned*)((char*)d_ws + 4096);
  unsigned* gbits = (unsigned*)((char*)d_ws + 4352);

  hipMemsetAsync(d_ws, 0, 8192, stream);   // zero counters + maxes (poisoned ws)
  fused_conv_kernel<<<NBLK, 256, 0, stream>>>(x, w, bias, out, leaf, root, gbits);
}

// Round 4
// 85.003 us; speedup vs baseline: 2.6944x; 1.2826x over previous
//
#include <hip/hip_runtime.h>

#define B_    16
#define CIN   64
#define COUT  128
#define H_    32
#define W_    32
#define NPB   256           // maxabs grid blocks

typedef __attribute__((ext_vector_type(4)))  int int4v;    // 16 int8 = 4 VGPRs
typedef __attribute__((ext_vector_type(16))) int int16v;   // 32x32 i8 MFMA C/D

// All-lanes max of a 256-entry array (written by maxabs), no LDS, no sync.
__device__ __forceinline__ float wave_max256(const float* __restrict__ p) {
  const int lane = threadIdx.x & 63;
  float m = fmaxf(fmaxf(p[lane], p[lane + 64]),
                  fmaxf(p[lane + 128], p[lane + 192]));
#pragma unroll
  for (int off = 32; off > 0; off >>= 1)
    m = fmaxf(m, __shfl_down(m, off, 64));
  return __shfl(m, 0, 64);
}

// ---------------------------------------------------------------------------
// Stage 1: per-block max|x|, max|w| -> bmx[256], bmw[256] (plain stores, no
// init needed, poison-safe). float4 loads, 256 blocks = 1 per CU.
// Cross-kernel visibility: implicit coherence at dispatch boundaries
// (verified in the round-0 pipeline).
// ---------------------------------------------------------------------------
__global__ __launch_bounds__(256) void maxabs_kernel(
    const float4* __restrict__ x4, const float4* __restrict__ w4,
    float* __restrict__ bmx, float* __restrict__ bmw) {
  const int nw4 = COUT * CIN * 9 / 4;       // 18432
  const int tid = blockIdx.x * 256 + threadIdx.x;
  float mx = 0.0f, mw = 0.0f;
#pragma unroll
  for (int k = 0; k < 4; ++k) {             // 262144 float4 / 65536 = 4
    float4 v = x4[tid + k * 65536];
    mx = fmaxf(mx, fmaxf(fmaxf(fabsf(v.x), fabsf(v.y)),
                         fmaxf(fabsf(v.z), fabsf(v.w))));
  }
  if (tid < nw4) {
    float4 v = w4[tid];
    mw = fmaxf(mw, fmaxf(fmaxf(fabsf(v.x), fabsf(v.y)),
                         fmaxf(fabsf(v.z), fabsf(v.w))));
  }
#pragma unroll
  for (int off = 32; off > 0; off >>= 1) {
    mx = fmaxf(mx, __shfl_down(mx, off, 64));
    mw = fmaxf(mw, __shfl_down(mw, off, 64));
  }
  __shared__ float smx[4], smw[4];
  const int wid = threadIdx.x >> 6;
  if ((threadIdx.x & 63) == 0) { smx[wid] = mx; smw[wid] = mw; }
  __syncthreads();
  if (threadIdx.x == 0) {
#pragma unroll
    for (int i = 1; i < 4; ++i) { mx = fmaxf(mx, smx[i]); mw = fmaxf(mw, smw[i]); }
    bmx[blockIdx.x] = mx;
    bmw[blockIdx.x] = mw;
  }
}

// ---------------------------------------------------------------------------
// Stage 2: quantize + pack weights only (non-redundant, 73728 elems, one per
// thread, 288 blocks). Exact reference semantics: IEEE div by max/127, rintf
// (round-half-even), clip +-127. Layout: qw s8 [s:9][c32:2][kb:2][o:128][16].
// ---------------------------------------------------------------------------
__global__ __launch_bounds__(256) void quantw_kernel(
    const float* __restrict__ w, const float* __restrict__ bmw,
    char* __restrict__ qw) {
  const int i = blockIdx.x * 256 + threadIdx.x;   // < 73728 = 288*256
  const float s = wave_max256(bmw) / 127.0f;
  float q = rintf(w[i] / s);
  q = fminf(fmaxf(q, -127.0f), 127.0f);
  // i = ((o*64 + c)*3 + kh)*3 + kw
  const int kw = i % 3; int j = i / 3;
  const int kh = j % 3; j /= 3;
  const int c = j & 63; const int o = j >> 6;
  const int sidx = kh * 3 + kw;
  const int c32 = c >> 5, kb = (c >> 4) & 1, e = c & 15;
  qw[(size_t)(((sidx * 2 + c32) * 2 + kb) * 128 + o) * 16 + e] = (char)(int)q;
}

// ---------------------------------------------------------------------------
// Stage 3: fused x-quant (block-local LDS, no qx global round-trip) + conv
// as 32x32x32 INT8 MFMA (exact: |q|<=127, i32 accum). Grid 512 = (b:16,
// yq:8, cq:4); 2 blocks/CU. Block: 4 output rows (yq*4..+3), 32 couts
// (cq*32..+31), 32 pixels. All 256 threads quantize the block's 6 halo rows
// of x into LDS qx_l (816 16-B chunks; lanes coalesced along xs; OOB ->
// zeros). Wave wid = one y row; A-frag from global qw (73 KB, L1/L2-hot,
// 512-B contiguous per half-wave); B-frag from LDS (contiguous b128,
// conflict-free). A: A[m=lane&31][k=(lane>>5)*16+j]; B: B[k][n=lane&31].
// D: col=lane&31 (pixel x), row=(reg&3)+8*(reg>>2)+4*(lane>>5) (cout).
// Two acc chains (exact integer sum). All geometry verified rounds 0-3.
// ---------------------------------------------------------------------------
__global__ __launch_bounds__(256, 2) void conv_kernel(
    const float* __restrict__ x, const char* __restrict__ qw,
    const float* __restrict__ bmx, const float* __restrict__ bmw,
    const float* __restrict__ bias, float* __restrict__ out) {
  const int t    = threadIdx.x;
  const int bb   = blockIdx.x;
  const int lane = t & 63;
  const int wid  = t >> 6;
  const int b  = bb >> 5;          // batch
  const int yq = (bb >> 2) & 7;    // y quad (rows yq*4 .. +3)
  const int cq = bb & 3;           // cout quarter (couts cq*32 .. +31)

  __shared__ __align__(16) char qx_l[13056];  // [r:6][c32:2][kb:2][xs:34][16]

  const float mx = wave_max256(bmx);
  const float mw = wave_max256(bmw);
  const float sx = mx / 127.0f;

  // ---- x-quant into LDS: rows yq*4-1 .. yq*4+4, 816 16-B chunks ----
#pragma unroll
  for (int k = 0; k < 4; ++k) {
    const int ch = t + k * 256;
    if (ch < 816) {
      const int r = ch / 136, rem = ch - r * 136;
      const int c32 = rem / 68, rem2 = rem - c32 * 68;
      const int kb = rem2 / 34, xs = rem2 - kb * 34;
      const int yy = yq * 4 - 1 + r;
      const int xx = xs - 1;
      unsigned d0 = 0, d1 = 0, d2 = 0, d3 = 0;
      if (yy >= 0 && yy <= 31 && xx >= 0 && xx <= 31) {
        const float* __restrict__ xp =
            x + ((size_t)((b * CIN + c32 * 32 + kb * 16) * H_ + yy) * W_) + xx;
#pragma unroll
        for (int e = 0; e < 16; ++e) {        // cin stride = H*W = 1024
          float q = rintf(xp[e * 1024] / sx);
          q = fminf(fmaxf(q, -127.0f), 127.0f);
          const unsigned byte = (unsigned)((int)q & 255) << ((e & 3) * 8);
          if (e < 4) d0 |= byte; else if (e < 8) d1 |= byte;
          else if (e < 12) d2 |= byte; else d3 |= byte;
        }
      }
      int4v val = {(int)d0, (int)d1, (int)d2, (int)d3};
      *(int4v*)(qx_l + (((r * 2 + c32) * 2 + kb) * 34 + xs) * 16) = val;
    }
  }
  __syncthreads();

  // ---- MFMA: wave wid -> row y = yq*4+wid ----
  {
    const int col = lane & 31;                 // pixel x / cout_local
    const int kb  = lane >> 5;                 // k-half within 32

    int16v acc0 = (int16v)0, acc1 = (int16v)0;

#pragma unroll
    for (int kh = 0; kh < 3; ++kh) {
      const int r = wid + kh;                  // qx_l row
#pragma unroll
      for (int kw = 0; kw < 3; ++kw) {
        const int s = kh * 3 + kw;
#pragma unroll
        for (int c32 = 0; c32 < 2; ++c32) {
          int4v a = *(const int4v*)(
              qw + (size_t)(((s * 2 + c32) * 2 + kb) * 128 + cq * 32 + col) * 16);
          int4v bf = *(const int4v*)(
              qx_l + (((r * 2 + c32) * 2 + kb) * 34 + col + kw) * 16);
          if (((s * 2 + c32) & 1) == 0)
            acc0 = __builtin_amdgcn_mfma_i32_32x32x32_i8(a, bf, acc0, 0, 0, 0);
          else
            acc1 = __builtin_amdgcn_mfma_i32_32x32x32_i8(a, bf, acc1, 0, 0, 0);
        }
      }
    }

    const float sc = sx * (mw / 127.0f);
    const int y = yq * 4 + wid;
#pragma unroll
    for (int rg = 0; rg < 16; ++rg) {
      const int row  = (rg & 3) + 8 * (rg >> 2) + 4 * kb;
      const int cout = cq * 32 + row;
      out[((b * COUT + cout) << 10) + y * W_ + col] =
          sc * (float)(acc0[rg] + acc1[rg]) + bias[cout];
    }
  }
}

// ---------------------------------------------------------------------------
extern "C" void kernel_launch(void* const* d_in, const int* in_sizes, int n_in,
                              void* d_out, int out_size, void* d_ws, size_t ws_size,
                              hipStream_t stream) {
  const float* x    = (const float*)d_in[0];
  const float* w    = (const float*)d_in[1];
  const float* bias = (const float*)d_in[2];
  float* out = (float*)d_out;

  // ws: bmx[256] | bmw[256] | qw s8 [9][2][2][128][16] (73.7 KB)
  // All ws bytes used are fully written before read -> poison-safe, no memset.
  float* bmx = (float*)d_ws;
  float* bmw = bmx + 256;
  char* qw = (char*)d_ws + 2048;

  maxabs_kernel<<<NPB, 256, 0, stream>>>((const float4*)x, (const float4*)w,
                                         bmx, bmw);
  quantw_kernel<<<288, 256, 0, stream>>>(w, bmw, qw);
  conv_kernel<<<512, 256, 0, stream>>>(x, qw, bmx, bmw, bias, out);
}